// Round 5
// baseline (148.094 us; speedup 1.0000x reference)
//
#include <hip/hip_runtime.h>

typedef _Float16 f16;
typedef _Float16 f16x8 __attribute__((ext_vector_type(8)));
typedef _Float16 f16x4 __attribute__((ext_vector_type(4)));
typedef float    f32x4 __attribute__((ext_vector_type(4)));

#define MFMA16(a, b, c) __builtin_amdgcn_mfma_f32_16x16x32_f16((a), (b), (c), 0, 0, 0)

// async global->LDS, 16B per lane; LDS dest is wave-uniform base + lane*16
__device__ __forceinline__ void gload16(const void* g, void* l) {
  __builtin_amdgcn_global_load_lds(
      (const __attribute__((address_space(1))) unsigned int*)g,
      (__attribute__((address_space(3))) unsigned int*)l, 16, 0, 0);
}

// ---------------- prep kernels ----------------

__global__ void cast_f32_f16(const float* __restrict__ in, f16* __restrict__ out, int n4) {
  int i = blockIdx.x * blockDim.x + threadIdx.x;
  if (i < n4) {
    float4 v = ((const float4*)in)[i];
    f16x4 o;
    o.x = (f16)v.x; o.y = (f16)v.y; o.z = (f16)v.z; o.w = (f16)v.w;
    ((f16x4*)out)[i] = o;
  }
}

// out[c][r] = (f16) in[r][c];  R rows, Cc cols of `in`; both multiples of 32
__global__ void transpose_cast(const float* __restrict__ in, f16* __restrict__ out, int R, int Cc) {
  __shared__ float tile[32][33];
  int c0 = blockIdx.x * 32, r0 = blockIdx.y * 32;
  int tx = threadIdx.x, ty = threadIdx.y;
#pragma unroll
  for (int i = ty; i < 32; i += 8)
    tile[i][tx] = in[(size_t)(r0 + i) * Cc + c0 + tx];
  __syncthreads();
#pragma unroll
  for (int i = ty; i < 32; i += 8)
    out[(size_t)(c0 + i) * R + r0 + tx] = (f16)tile[tx][i];
}

// ---------------- shared GEMM core ----------------
// C[128x128] tile = A[bm*128.., K] * Bt[bn*128.., K]^T, K = KDIM, fp16 in, f32 acc.
// LDS layout: [row][64] f16, content swizzled: LDS(row, kb) = global(row, kb ^ ((row&7)<<4)) bytes.
template <int KDIM>
__device__ __forceinline__ void gemm_core(const f16* __restrict__ A, const f16* __restrict__ Bt,
                                          int bm, int bn, f16* lA, f16* lB, f32x4 acc[4][4]) {
  const int t = threadIdx.x, lane = t & 63, wave = t >> 6;
  const int wm = wave >> 1, wn = wave & 1;
  const int srow = lane >> 3;            // row within 8-row chunk
  const int skb = (lane & 7) * 16;       // byte offset within 128B row
  const int nkt = KDIM / 64;
  for (int kt = 0; kt < nkt; ++kt) {
    __syncthreads();
#pragma unroll
    for (int c = 0; c < 4; ++c) {
      int cc = c * 4 + wave;             // 0..15, wave-uniform
      int row = cc * 8 + srow;           // 0..127
      int kbs = skb ^ ((row & 7) << 4);  // pre-swizzled source byte offset
      gload16((const char*)A + (size_t)(bm * 128 + row) * (KDIM * 2) + kt * 128 + kbs,
              lA + cc * 512);
      gload16((const char*)Bt + (size_t)(bn * 128 + row) * (KDIM * 2) + kt * 128 + kbs,
              lB + cc * 512);
    }
    __syncthreads();
#pragma unroll
    for (int ks = 0; ks < 2; ++ks) {
      f16x8 af[4], bf[4];
#pragma unroll
      for (int mi = 0; mi < 4; ++mi) {
        int r = wm * 64 + mi * 16 + (lane & 15);
        int ke = (ks * 32 + ((lane >> 4) << 3)) ^ ((r & 7) << 3);  // elements
        af[mi] = *(const f16x8*)&lA[r * 64 + ke];
      }
#pragma unroll
      for (int ni = 0; ni < 4; ++ni) {
        int r = wn * 64 + ni * 16 + (lane & 15);
        int ke = (ks * 32 + ((lane >> 4) << 3)) ^ ((r & 7) << 3);
        bf[ni] = *(const f16x8*)&lB[r * 64 + ke];
      }
#pragma unroll
      for (int mi = 0; mi < 4; ++mi)
#pragma unroll
        for (int ni = 0; ni < 4; ++ni)
          acc[mi][ni] = MFMA16(af[mi], bf[ni], acc[mi][ni]);
    }
  }
}

// ---------------- QKV projection ----------------
// A = x_f16 [4096,1024]; Bt = w_qkv^T [3072,1024].
// Scatter: sec0 -> Q[B,H,N,D]*0.125 ; sec1 -> K[B,H,N,D] ; sec2 -> V^T[B,H,D,N]
__global__ __launch_bounds__(256, 2) void gemm_qkv(const f16* __restrict__ A,
                                                   const f16* __restrict__ Bt,
                                                   f16* __restrict__ Qo, f16* __restrict__ Ko,
                                                   f16* __restrict__ Vt) {
  __shared__ __align__(16) f16 lA[128 * 64];
  __shared__ __align__(16) f16 lB[128 * 64];
  f32x4 acc[4][4] = {};
  int bn = blockIdx.x, bm = blockIdx.y;
  gemm_core<1024>(A, Bt, bm, bn, lA, lB, acc);
  int lane = threadIdx.x & 63, wave = threadIdx.x >> 6;
  int wm = wave >> 1, wn = wave & 1;
  int sec = (bn * 128) >> 10;  // 0=Q 1=K 2=V, uniform per block (128 | 1024)
  float scl = (sec == 0) ? 0.125f : 1.0f;
#pragma unroll
  for (int mi = 0; mi < 4; ++mi)
#pragma unroll
    for (int ni = 0; ni < 4; ++ni)
#pragma unroll
      for (int reg = 0; reg < 4; ++reg) {
        int gr = bm * 128 + wm * 64 + mi * 16 + ((lane >> 4) << 2) + reg;  // [0,4096)
        int gc = bn * 128 + wn * 64 + ni * 16 + (lane & 15);               // [0,3072)
        int b = gr >> 11, n = gr & 2047;
        int jj = gc & 1023;
        int h = jj >> 6, d = jj & 63;
        f16 v = (f16)(acc[mi][ni][reg] * scl);
        size_t bh = (size_t)(b * 16 + h);
        if (sec == 0)      Qo[(bh * 2048 + n) * 64 + d] = v;
        else if (sec == 1) Ko[(bh * 2048 + n) * 64 + d] = v;
        else               Vt[(bh * 64 + d) * 2048 + n] = v;
      }
}

// ---------------- causal flash attention ----------------
// Q pre-scaled by 0.125. Q,K: [B,H,N,D] f16; Vt: [B,H,D,N] f16; Ob: [N,C] slice f16.
// One q-tile of 64 rows; 4 waves x 16 rows. KV tiles of 64, double-buffered, 1 barrier/tile.
__device__ __forceinline__ void attn_one(const f16* __restrict__ Qb, const f16* __restrict__ Kb,
                                         const f16* __restrict__ Vb, f16* __restrict__ Ob,
                                         int qt, int lane, int wave,
                                         f16* lK, f16* lV, f16* pP) {
  const int N = 2048;
  const int wq0 = qt * 64 + wave * 16;
  f16x8 qf[2];
#pragma unroll
  for (int ks = 0; ks < 2; ++ks)
    qf[ks] = *(const f16x8*)&Qb[(size_t)(wq0 + (lane & 15)) * 64 + ks * 32 + ((lane >> 4) << 3)];
  f32x4 oacc[4] = {};
  float mrun[4], lrun[4];
#pragma unroll
  for (int r = 0; r < 4; ++r) { mrun[r] = -1e30f; lrun[r] = 0.f; }
  const int srow = lane >> 3, skb = (lane & 7) * 16;
  const int ntiles = qt + 1;

  auto STAGE = [&](int buf, int kv) {
    int kv0 = kv << 6;
#pragma unroll
    for (int c = 0; c < 2; ++c) {
      int cc = c * 4 + wave;             // 0..7, wave-uniform
      int row = cc * 8 + srow;           // 0..63
      int kbs = skb ^ ((row & 7) << 4);  // pre-swizzled source
      gload16((const char*)Kb + (size_t)(kv0 + row) * 128 + kbs, lK + buf * 4096 + cc * 512);
      gload16((const char*)Vb + (size_t)row * (N * 2) + (size_t)kv0 * 2 + kbs,
              lV + buf * 4096 + cc * 512);
    }
  };

  STAGE(0, 0);
  __syncthreads();  // drains vmcnt before barrier (compiler)
  for (int kv = 0; kv < ntiles; ++kv) {
    int cur = kv & 1;
    if (kv + 1 < ntiles) STAGE(cur ^ 1, kv + 1);  // prefetch next tile
    const f16* K0 = lK + cur * 4096;
    const f16* V0 = lV + cur * 4096;
    int kv0 = kv << 6;
    f32x4 s[4] = {};
    __builtin_amdgcn_s_setprio(1);
#pragma unroll
    for (int ks = 0; ks < 2; ++ks) {
      f16x8 kf[4];
#pragma unroll
      for (int ni = 0; ni < 4; ++ni) {
        int r = ni * 16 + (lane & 15);
        int ke = (ks * 32 + ((lane >> 4) << 3)) ^ ((r & 7) << 3);
        kf[ni] = *(const f16x8*)&K0[r * 64 + ke];
      }
#pragma unroll
      for (int ni = 0; ni < 4; ++ni) s[ni] = MFMA16(qf[ks], kf[ni], s[ni]);
    }
    __builtin_amdgcn_s_setprio(0);
    if (kv == qt) {  // diagonal tile: causal mask
#pragma unroll
      for (int ni = 0; ni < 4; ++ni)
#pragma unroll
        for (int reg = 0; reg < 4; ++reg) {
          int gq = wq0 + ((lane >> 4) << 2) + reg;
          int gk = kv0 + ni * 16 + (lane & 15);
          if (gk > gq) s[ni][reg] = -1e30f;
        }
    }
    // online softmax: rows on (lane>>4)*4+reg; key-cols on lane&15 (16-lane shfl reduce)
    float mx[4], corr[4], rsum[4];
#pragma unroll
    for (int reg = 0; reg < 4; ++reg)
      mx[reg] = fmaxf(fmaxf(s[0][reg], s[1][reg]), fmaxf(s[2][reg], s[3][reg]));
#pragma unroll
    for (int off = 1; off < 16; off <<= 1)
#pragma unroll
      for (int reg = 0; reg < 4; ++reg) mx[reg] = fmaxf(mx[reg], __shfl_xor(mx[reg], off));
#pragma unroll
    for (int reg = 0; reg < 4; ++reg) {
      float mnew = fmaxf(mrun[reg], mx[reg]);
      corr[reg] = __expf(mrun[reg] - mnew);
      mrun[reg] = mnew;
      rsum[reg] = 0.f;
    }
#pragma unroll
    for (int ni = 0; ni < 4; ++ni)
#pragma unroll
      for (int reg = 0; reg < 4; ++reg) {
        float p = __expf(s[ni][reg] - mrun[reg]);
        s[ni][reg] = p;
        rsum[reg] += p;
      }
#pragma unroll
    for (int off = 1; off < 16; off <<= 1)
#pragma unroll
      for (int reg = 0; reg < 4; ++reg) rsum[reg] += __shfl_xor(rsum[reg], off);
#pragma unroll
    for (int reg = 0; reg < 4; ++reg) lrun[reg] = lrun[reg] * corr[reg] + rsum[reg];
#pragma unroll
    for (int ni = 0; ni < 4; ++ni)
#pragma unroll
      for (int reg = 0; reg < 4; ++reg) oacc[ni][reg] *= corr[reg];
    // P -> per-wave LDS (swizzled) to reshape D-frag -> A-frag
#pragma unroll
    for (int ni = 0; ni < 4; ++ni)
#pragma unroll
      for (int reg = 0; reg < 4; ++reg) {
        int pr = ((lane >> 4) << 2) + reg;
        int pc = ni * 16 + (lane & 15);
        pP[pr * 64 + (pc ^ ((pr & 7) << 3))] = (f16)s[ni][reg];
      }
    asm volatile("s_waitcnt lgkmcnt(0)" ::: "memory");
    // O += P @ V
    __builtin_amdgcn_s_setprio(1);
#pragma unroll
    for (int ks = 0; ks < 2; ++ks) {
      f16x8 pf, vf[4];
      {
        int r = lane & 15;
        int ke = (ks * 32 + ((lane >> 4) << 3)) ^ ((r & 7) << 3);
        pf = *(const f16x8*)&pP[r * 64 + ke];
      }
#pragma unroll
      for (int ni = 0; ni < 4; ++ni) {
        int r = ni * 16 + (lane & 15);
        int ke = (ks * 32 + ((lane >> 4) << 3)) ^ ((r & 7) << 3);
        vf[ni] = *(const f16x8*)&V0[r * 64 + ke];
      }
#pragma unroll
      for (int ni = 0; ni < 4; ++ni) oacc[ni] = MFMA16(pf, vf[ni], oacc[ni]);
    }
    __builtin_amdgcn_s_setprio(0);
    __syncthreads();  // staging for next tile complete; reads of cur done in all waves
  }
  // epilogue: Ob[n, h*64+d] (Ob pre-offset to this b,h)
#pragma unroll
  for (int reg = 0; reg < 4; ++reg) {
    float inv = 1.0f / lrun[reg];
    int gq = wq0 + ((lane >> 4) << 2) + reg;
#pragma unroll
    for (int ni = 0; ni < 4; ++ni) {
      int d = ni * 16 + (lane & 15);
      Ob[(size_t)gq * 1024 + d] = (f16)(oacc[ni][reg] * inv);
    }
  }
}

// 1024 blocks, one 64-row q-tile each -> 4 blocks/CU = 4 independent chains/SIMD.
// XCD-chunked (T1): c = w&7 owns heads [4c,4c+4) -> 2 MB K/V working set per XCD L2.
// Balance vs breadth-first dispatch: CU k of an XCD gets j = {k, k+32, k+64, k+96}
// (head quadrants 0..3); odd quadrants use complemented q-tile -> per-CU load
// {x, 31-x, x, 31-x} = uniform 66 KV-tile-units.
__global__ __launch_bounds__(256, 4) void attn(const f16* __restrict__ Q,
                                               const f16* __restrict__ K,
                                               const f16* __restrict__ Vt,
                                               f16* __restrict__ O) {
  __shared__ __align__(16) f16 lK[2 * 4096];
  __shared__ __align__(16) f16 lV[2 * 4096];
  __shared__ __align__(16) f16 lP[4 * 1024];
  int w = blockIdx.x;             // 0..1023
  int c = w & 7, j = w >> 3;      // XCD chunk id, index within chunk [0,128)
  int quad = j >> 5;              // head quadrant 0..3
  int x = j & 31;                 // q-tile index within head
  int bh = c * 4 + quad;
  int qt = (quad & 1) ? (31 - x) : x;
  int b = bh >> 4, h = bh & 15;
  int lane = threadIdx.x & 63, wave = threadIdx.x >> 6;
  const f16* Qb = Q + (size_t)bh * 2048 * 64;
  const f16* Kb = K + (size_t)bh * 2048 * 64;
  const f16* Vb = Vt + (size_t)bh * 2048 * 64;
  f16* Ob = O + (size_t)b * 2048 * 1024 + h * 64;
  f16* pP = lP + wave * 1024;
  attn_one(Qb, Kb, Vb, Ob, qt, lane, wave, lK, lV, pP);
}

// ---------------- output projection ----------------
__global__ __launch_bounds__(256, 2) void gemm_out(const f16* __restrict__ A,
                                                   const f16* __restrict__ Bt,
                                                   const float* __restrict__ bias,
                                                   float* __restrict__ out) {
  __shared__ __align__(16) f16 lA[128 * 64];
  __shared__ __align__(16) f16 lB[128 * 64];
  f32x4 acc[4][4] = {};
  int bn = blockIdx.x, bm = blockIdx.y;
  gemm_core<1024>(A, Bt, bm, bn, lA, lB, acc);
  int lane = threadIdx.x & 63, wave = threadIdx.x >> 6;
  int wm = wave >> 1, wn = wave & 1;
#pragma unroll
  for (int mi = 0; mi < 4; ++mi)
#pragma unroll
    for (int ni = 0; ni < 4; ++ni)
#pragma unroll
      for (int reg = 0; reg < 4; ++reg) {
        int gr = bm * 128 + wm * 64 + mi * 16 + ((lane >> 4) << 2) + reg;
        int gc = bn * 128 + wn * 64 + ni * 16 + (lane & 15);
        out[(size_t)gr * 1024 + gc] = acc[mi][ni][reg] + bias[gc];
      }
}

// ---------------- launcher ----------------
extern "C" void kernel_launch(void* const* d_in, const int* in_sizes, int n_in,
                              void* d_out, int out_size, void* d_ws, size_t ws_size,
                              hipStream_t stream) {
  const float* x     = (const float*)d_in[0];  // [2,2048,1024]
  const float* w_qkv = (const float*)d_in[1];  // [1024,3072]
  const float* w_out = (const float*)d_in[2];  // [1024,1024]
  const float* b_out = (const float*)d_in[3];  // [1024]
  // d_in[4] = attn_mask (causal; computed analytically)
  float* out = (float*)d_out;
  char* ws = (char*)d_ws;

  f16* xh    = (f16*)(ws);                   //  8 MB [4096,1024]
  f16* wqkvT = (f16*)(ws + (8u << 20));      //  6 MB [3072,1024]
  f16* woutT = (f16*)(ws + (14u << 20));     //  2 MB [1024,1024]
  f16* Qs    = (f16*)(ws + (16u << 20));     //  8 MB [B,H,N,D] (pre-scaled)
  f16* Ks    = (f16*)(ws + (24u << 20));     //  8 MB [B,H,N,D]
  f16* Vts   = (f16*)(ws + (32u << 20));     //  8 MB [B,H,D,N]
  f16* Oa    = (f16*)(ws + (40u << 20));     //  8 MB [B,N,H*D]

  cast_f32_f16<<<4096, 256, 0, stream>>>(x, xh, 1048576);
  transpose_cast<<<dim3(96, 32), dim3(32, 8), 0, stream>>>(w_qkv, wqkvT, 1024, 3072);
  transpose_cast<<<dim3(32, 32), dim3(32, 8), 0, stream>>>(w_out, woutT, 1024, 1024);
  gemm_qkv<<<dim3(24, 32), 256, 0, stream>>>(xh, wqkvT, Qs, Ks, Vts);
  attn<<<1024, 256, 0, stream>>>(Qs, Ks, Vts, Oa);
  gemm_out<<<dim3(8, 32), 256, 0, stream>>>(Oa, woutT, b_out, out);
}

// Round 6
// 117.961 us; speedup vs baseline: 1.2555x; 1.2555x over previous
//
#include <hip/hip_runtime.h>

typedef _Float16 f16;
typedef _Float16 f16x8 __attribute__((ext_vector_type(8)));
typedef _Float16 f16x4 __attribute__((ext_vector_type(4)));
typedef float    f32x4 __attribute__((ext_vector_type(4)));

#define MFMA16(a, b, c) __builtin_amdgcn_mfma_f32_16x16x32_f16((a), (b), (c), 0, 0, 0)

// async global->LDS, 16B per lane; LDS dest is wave-uniform base + lane*16
__device__ __forceinline__ void gload16(const void* g, void* l) {
  __builtin_amdgcn_global_load_lds(
      (const __attribute__((address_space(1))) unsigned int*)g,
      (__attribute__((address_space(3))) unsigned int*)l, 16, 0, 0);
}

// ---------------- prep kernels ----------------

__global__ void cast_f32_f16(const float* __restrict__ in, f16* __restrict__ out, int n4) {
  int i = blockIdx.x * blockDim.x + threadIdx.x;
  if (i < n4) {
    float4 v = ((const float4*)in)[i];
    f16x4 o;
    o.x = (f16)v.x; o.y = (f16)v.y; o.z = (f16)v.z; o.w = (f16)v.w;
    ((f16x4*)out)[i] = o;
  }
}

// out[c][r] = (f16) in[r][c];  R rows, Cc cols of `in`; both multiples of 32
__global__ void transpose_cast(const float* __restrict__ in, f16* __restrict__ out, int R, int Cc) {
  __shared__ float tile[32][33];
  int c0 = blockIdx.x * 32, r0 = blockIdx.y * 32;
  int tx = threadIdx.x, ty = threadIdx.y;
#pragma unroll
  for (int i = ty; i < 32; i += 8)
    tile[i][tx] = in[(size_t)(r0 + i) * Cc + c0 + tx];
  __syncthreads();
#pragma unroll
  for (int i = ty; i < 32; i += 8)
    out[(size_t)(c0 + i) * R + r0 + tx] = (f16)tile[tx][i];
}

// ---------------- shared GEMM core ----------------
// C[128x128] tile = A[bm*128.., K] * Bt[bn*128.., K]^T, K = KDIM, fp16 in, f32 acc.
// LDS layout: [row][64] f16, content swizzled: LDS(row, kb) = global(row, kb ^ ((row&7)<<4)) bytes.
template <int KDIM>
__device__ __forceinline__ void gemm_core(const f16* __restrict__ A, const f16* __restrict__ Bt,
                                          int bm, int bn, f16* lA, f16* lB, f32x4 acc[4][4]) {
  const int t = threadIdx.x, lane = t & 63, wave = t >> 6;
  const int wm = wave >> 1, wn = wave & 1;
  const int srow = lane >> 3;            // row within 8-row chunk
  const int skb = (lane & 7) * 16;       // byte offset within 128B row
  const int nkt = KDIM / 64;
  for (int kt = 0; kt < nkt; ++kt) {
    __syncthreads();
#pragma unroll
    for (int c = 0; c < 4; ++c) {
      int cc = c * 4 + wave;             // 0..15, wave-uniform
      int row = cc * 8 + srow;           // 0..127
      int kbs = skb ^ ((row & 7) << 4);  // pre-swizzled source byte offset
      gload16((const char*)A + (size_t)(bm * 128 + row) * (KDIM * 2) + kt * 128 + kbs,
              lA + cc * 512);
      gload16((const char*)Bt + (size_t)(bn * 128 + row) * (KDIM * 2) + kt * 128 + kbs,
              lB + cc * 512);
    }
    __syncthreads();
#pragma unroll
    for (int ks = 0; ks < 2; ++ks) {
      f16x8 af[4], bf[4];
#pragma unroll
      for (int mi = 0; mi < 4; ++mi) {
        int r = wm * 64 + mi * 16 + (lane & 15);
        int ke = (ks * 32 + ((lane >> 4) << 3)) ^ ((r & 7) << 3);  // elements
        af[mi] = *(const f16x8*)&lA[r * 64 + ke];
      }
#pragma unroll
      for (int ni = 0; ni < 4; ++ni) {
        int r = wn * 64 + ni * 16 + (lane & 15);
        int ke = (ks * 32 + ((lane >> 4) << 3)) ^ ((r & 7) << 3);
        bf[ni] = *(const f16x8*)&lB[r * 64 + ke];
      }
#pragma unroll
      for (int mi = 0; mi < 4; ++mi)
#pragma unroll
        for (int ni = 0; ni < 4; ++ni)
          acc[mi][ni] = MFMA16(af[mi], bf[ni], acc[mi][ni]);
    }
  }
}

// ---------------- QKV projection ----------------
// A = x_f16 [4096,1024]; Bt = w_qkv^T [3072,1024].
// sec0 -> Q[B,H,N,D]*0.125 ; sec1 -> K[B,H,N,D] ;
// sec2 -> V^T[B,H,D,N] with key index permuted within 32-blocks:
//   p(n) = 8*((n>>2)&3) + 4*((n>>4)&1) + (n&3)
// so that attention's PV B-fragment is lane-local (see attn_one).
__global__ __launch_bounds__(256, 2) void gemm_qkv(const f16* __restrict__ A,
                                                   const f16* __restrict__ Bt,
                                                   f16* __restrict__ Qo, f16* __restrict__ Ko,
                                                   f16* __restrict__ Vt) {
  __shared__ __align__(16) f16 lA[128 * 64];
  __shared__ __align__(16) f16 lB[128 * 64];
  f32x4 acc[4][4] = {};
  int bn = blockIdx.x, bm = blockIdx.y;
  gemm_core<1024>(A, Bt, bm, bn, lA, lB, acc);
  int lane = threadIdx.x & 63, wave = threadIdx.x >> 6;
  int wm = wave >> 1, wn = wave & 1;
  int sec = (bn * 128) >> 10;  // 0=Q 1=K 2=V, uniform per block (128 | 1024)
  float scl = (sec == 0) ? 0.125f : 1.0f;
#pragma unroll
  for (int mi = 0; mi < 4; ++mi)
#pragma unroll
    for (int ni = 0; ni < 4; ++ni)
#pragma unroll
      for (int reg = 0; reg < 4; ++reg) {
        int gr = bm * 128 + wm * 64 + mi * 16 + ((lane >> 4) << 2) + reg;  // [0,4096)
        int gc = bn * 128 + wn * 64 + ni * 16 + (lane & 15);               // [0,3072)
        int b = gr >> 11, n = gr & 2047;
        int jj = gc & 1023;
        int h = jj >> 6, d = jj & 63;
        f16 v = (f16)(acc[mi][ni][reg] * scl);
        size_t bh = (size_t)(b * 16 + h);
        if (sec == 0)      Qo[(bh * 2048 + n) * 64 + d] = v;
        else if (sec == 1) Ko[(bh * 2048 + n) * 64 + d] = v;
        else {
          int np = (n & ~31) | (((n >> 2) & 3) << 3) | (((n >> 4) & 1) << 2) | (n & 3);
          Vt[(bh * 64 + d) * 2048 + np] = v;
        }
      }
}

// ---------------- causal flash attention ----------------
// Q pre-scaled by 0.125. Q,K: [B,H,N,D] f16; Vt: [B,H,D,N] f16 (key-permuted); Ob: [N,C] slice.
// Swapped-operand scheme: S^T = mfma(K, Q) puts a full q-row's scores on the
// lane column (q = lane&15; k = kv0 + 16*ni + 4*(lane>>4) + reg). Softmax is
// 15 in-reg ops + 2 shfl_xor; m/l/corr are per-lane scalars. The softmaxed
// regs are DIRECTLY the PV B-fragment because V's key columns are stored
// permuted to match (contraction order is irrelevant if A and B agree).
__device__ __forceinline__ void attn_one(const f16* __restrict__ Qb, const f16* __restrict__ Kb,
                                         const f16* __restrict__ Vb, f16* __restrict__ Ob,
                                         int qt, int lane, int wave, f16* lK, f16* lV) {
  const int N = 2048;
  const int wq0 = qt * 64 + wave * 16;
  const int g = lane >> 4, q15 = lane & 15;
  f16x8 qf[2];
#pragma unroll
  for (int ks = 0; ks < 2; ++ks)
    qf[ks] = *(const f16x8*)&Qb[(size_t)(wq0 + q15) * 64 + ks * 32 + (g << 3)];
  f32x4 oacc[4] = {};
  float mrun = -1e30f, lrun = 0.f;
  const int srow = lane >> 3, skb = (lane & 7) * 16;
  const int ntiles = qt + 1;

  auto STAGE = [&](int buf, int kv) {
    int kv0 = kv << 6;
#pragma unroll
    for (int c = 0; c < 2; ++c) {
      int cc = c * 4 + wave;             // 0..7, wave-uniform
      int row = cc * 8 + srow;           // 0..63
      int kbs = skb ^ ((row & 7) << 4);  // pre-swizzled source
      gload16((const char*)Kb + (size_t)(kv0 + row) * 128 + kbs, lK + buf * 4096 + cc * 512);
      gload16((const char*)Vb + (size_t)row * (N * 2) + (size_t)kv0 * 2 + kbs,
              lV + buf * 4096 + cc * 512);
    }
  };

  STAGE(0, 0);
  __syncthreads();
  for (int kv = 0; kv < ntiles; ++kv) {
    int cur = kv & 1;
    if (kv + 1 < ntiles) STAGE(cur ^ 1, kv + 1);  // prefetch next tile
    const f16* K0 = lK + cur * 4096;
    const f16* V0 = lV + cur * 4096;
    int kv0 = kv << 6;
    f32x4 s[4] = {};
    __builtin_amdgcn_s_setprio(1);
#pragma unroll
    for (int ks = 0; ks < 2; ++ks) {
      f16x8 kf[4];
#pragma unroll
      for (int ni = 0; ni < 4; ++ni) {
        int r = ni * 16 + q15;                       // key row 0..63
        int ke = (ks * 32 + (g << 3)) ^ ((r & 7) << 3);
        kf[ni] = *(const f16x8*)&K0[r * 64 + ke];
      }
#pragma unroll
      for (int ni = 0; ni < 4; ++ni) s[ni] = MFMA16(kf[ni], qf[ks], s[ni]);  // S^T[k][q]
    }
    __builtin_amdgcn_s_setprio(0);
    if (kv == qt) {  // diagonal tile: causal mask. k = kv0+16ni+4g+reg, q = wq0+q15.
      int gq = wq0 + q15;
#pragma unroll
      for (int ni = 0; ni < 4; ++ni)
#pragma unroll
        for (int reg = 0; reg < 4; ++reg) {
          int gk = kv0 + ni * 16 + g * 4 + reg;
          if (gk > gq) s[ni][reg] = -1e30f;
        }
    }
    // per-lane softmax over 16 regs + 2 shfl (lanes l, l+16, l+32, l+48 share q)
    f32x4 m4 = s[0];
#pragma unroll
    for (int ni = 1; ni < 4; ++ni)
#pragma unroll
      for (int reg = 0; reg < 4; ++reg) m4[reg] = fmaxf(m4[reg], s[ni][reg]);
    float mx = fmaxf(fmaxf(m4[0], m4[1]), fmaxf(m4[2], m4[3]));
    mx = fmaxf(mx, __shfl_xor(mx, 16));
    mx = fmaxf(mx, __shfl_xor(mx, 32));
    float mnew = fmaxf(mrun, mx);
    float corr = __expf(mrun - mnew);
    mrun = mnew;
    float rsum = 0.f;
#pragma unroll
    for (int ni = 0; ni < 4; ++ni)
#pragma unroll
      for (int reg = 0; reg < 4; ++reg) {
        float p = __expf(s[ni][reg] - mnew);
        s[ni][reg] = p;
        rsum += p;
      }
    rsum += __shfl_xor(rsum, 16);
    rsum += __shfl_xor(rsum, 32);
    lrun = lrun * corr + rsum;
#pragma unroll
    for (int ni = 0; ni < 4; ++ni)
#pragma unroll
      for (int reg = 0; reg < 4; ++reg) oacc[ni][reg] *= corr;
    // pack P fragments (lane-local; order matches permuted V layout)
    f16x8 pf[2];
#pragma unroll
    for (int ks = 0; ks < 2; ++ks)
#pragma unroll
      for (int e = 0; e < 8; ++e) pf[ks][e] = (f16)s[2 * ks + (e >> 2)][e & 3];
    // O^T[d][q] += V^T_perm @ P  (A = V rows d from LDS, B = pf in-register)
    __builtin_amdgcn_s_setprio(1);
#pragma unroll
    for (int ks = 0; ks < 2; ++ks) {
      f16x8 vf[4];
#pragma unroll
      for (int mi = 0; mi < 4; ++mi) {
        int r = mi * 16 + q15;                       // d row 0..63
        int ke = (ks * 32 + (g << 3)) ^ ((r & 7) << 3);
        vf[mi] = *(const f16x8*)&V0[r * 64 + ke];
      }
#pragma unroll
      for (int mi = 0; mi < 4; ++mi) oacc[mi] = MFMA16(vf[mi], pf[ks], oacc[mi]);
    }
    __builtin_amdgcn_s_setprio(0);
    __syncthreads();  // staging for next tile complete; reads of cur done in all waves
  }
  // epilogue: O^T[d][q] -> Ob[q, d]; d = 16*mi + 4*g + reg (4 contiguous per mi)
  float inv = 1.0f / lrun;
  int gq = wq0 + q15;
#pragma unroll
  for (int mi = 0; mi < 4; ++mi) {
    f16x4 o4;
#pragma unroll
    for (int reg = 0; reg < 4; ++reg) o4[reg] = (f16)(oacc[mi][reg] * inv);
    *(f16x4*)&Ob[(size_t)gq * 1024 + mi * 16 + g * 4] = o4;
  }
}

// 1D grid, XCD-chunked (T1): XCD c = w&7 exclusively owns heads bh in [4c, 4c+4),
// so each XCD's L2 working set is 4 heads * (K+V = 512 KB) = 2 MB < 4 MB.
// Pair-balanced q-tiles {31-x, x}: uniform 33 KV tiles per block, 2 blocks/CU.
__global__ __launch_bounds__(256, 2) void attn(const f16* __restrict__ Q,
                                               const f16* __restrict__ K,
                                               const f16* __restrict__ Vt,
                                               f16* __restrict__ O) {
  __shared__ __align__(16) f16 lK[2 * 4096];
  __shared__ __align__(16) f16 lV[2 * 4096];
  int w = blockIdx.x;            // 0..511
  int c = w & 7, j = w >> 3;     // XCD chunk id, index within chunk
  int bh = c * 4 + (j >> 4);     // 4 heads per XCD
  int x = j & 15;                // pair index within head
  int b = bh >> 4, h = bh & 15;
  int lane = threadIdx.x & 63, wave = threadIdx.x >> 6;
  const f16* Qb = Q + (size_t)bh * 2048 * 64;
  const f16* Kb = K + (size_t)bh * 2048 * 64;
  const f16* Vb = Vt + (size_t)bh * 2048 * 64;
  f16* Ob = O + (size_t)b * 2048 * 1024 + h * 64;
  attn_one(Qb, Kb, Vb, Ob, 31 - x, lane, wave, lK, lV);
  attn_one(Qb, Kb, Vb, Ob, x, lane, wave, lK, lV);
}

// ---------------- output projection ----------------
__global__ __launch_bounds__(256, 2) void gemm_out(const f16* __restrict__ A,
                                                   const f16* __restrict__ Bt,
                                                   const float* __restrict__ bias,
                                                   float* __restrict__ out) {
  __shared__ __align__(16) f16 lA[128 * 64];
  __shared__ __align__(16) f16 lB[128 * 64];
  f32x4 acc[4][4] = {};
  int bn = blockIdx.x, bm = blockIdx.y;
  gemm_core<1024>(A, Bt, bm, bn, lA, lB, acc);
  int lane = threadIdx.x & 63, wave = threadIdx.x >> 6;
  int wm = wave >> 1, wn = wave & 1;
#pragma unroll
  for (int mi = 0; mi < 4; ++mi)
#pragma unroll
    for (int ni = 0; ni < 4; ++ni)
#pragma unroll
      for (int reg = 0; reg < 4; ++reg) {
        int gr = bm * 128 + wm * 64 + mi * 16 + ((lane >> 4) << 2) + reg;
        int gc = bn * 128 + wn * 64 + ni * 16 + (lane & 15);
        out[(size_t)gr * 1024 + gc] = acc[mi][ni][reg] + bias[gc];
      }
}

// ---------------- launcher ----------------
extern "C" void kernel_launch(void* const* d_in, const int* in_sizes, int n_in,
                              void* d_out, int out_size, void* d_ws, size_t ws_size,
                              hipStream_t stream) {
  const float* x     = (const float*)d_in[0];  // [2,2048,1024]
  const float* w_qkv = (const float*)d_in[1];  // [1024,3072]
  const float* w_out = (const float*)d_in[2];  // [1024,1024]
  const float* b_out = (const float*)d_in[3];  // [1024]
  // d_in[4] = attn_mask (causal; computed analytically)
  float* out = (float*)d_out;
  char* ws = (char*)d_ws;

  f16* xh    = (f16*)(ws);                   //  8 MB [4096,1024]
  f16* wqkvT = (f16*)(ws + (8u << 20));      //  6 MB [3072,1024]
  f16* woutT = (f16*)(ws + (14u << 20));     //  2 MB [1024,1024]
  f16* Qs    = (f16*)(ws + (16u << 20));     //  8 MB [B,H,N,D] (pre-scaled)
  f16* Ks    = (f16*)(ws + (24u << 20));     //  8 MB [B,H,N,D]
  f16* Vts   = (f16*)(ws + (32u << 20));     //  8 MB [B,H,D,N] (key-permuted)
  f16* Oa    = (f16*)(ws + (40u << 20));     //  8 MB [B,N,H*D]

  cast_f32_f16<<<4096, 256, 0, stream>>>(x, xh, 1048576);
  transpose_cast<<<dim3(96, 32), dim3(32, 8), 0, stream>>>(w_qkv, wqkvT, 1024, 3072);
  transpose_cast<<<dim3(32, 32), dim3(32, 8), 0, stream>>>(w_out, woutT, 1024, 1024);
  gemm_qkv<<<dim3(24, 32), 256, 0, stream>>>(xh, wqkvT, Qs, Ks, Vts);
  attn<<<512, 256, 0, stream>>>(Qs, Ks, Vts, Oa);
  gemm_out<<<dim3(8, 32), 256, 0, stream>>>(Oa, woutT, b_out, out);
}